// Round 10
// baseline (172.773 us; speedup 1.0000x reference)
//
#include <hip/hip_runtime.h>
#include <math.h>

#define T_TOK 1024   // B*S
#define D 512        // D_IN = D_OUT
#define EPS 1e-5f
#define NBLK_P 512   // persistent blocks: 2/CU guaranteed co-resident (LDS 37KB -> 4/CU cap)

typedef short bf16x8 __attribute__((ext_vector_type(8)));
typedef float f32x4  __attribute__((ext_vector_type(4)));

__device__ __forceinline__ unsigned short f2bf(float f) {
    unsigned int u = __builtin_bit_cast(unsigned int, f);
    u += 0x7FFFu + ((u >> 16) & 1u);   // RNE
    return (unsigned short)(u >> 16);
}
__device__ __forceinline__ float bf2f(unsigned short h) {
    return __builtin_bit_cast(float, (unsigned int)h << 16);
}

// Software grid barrier (persistent kernel; all NBLK_P blocks co-resident).
// Device-scope release fence -> atomic arrive -> spin on device-scope load
// -> acquire fence. Counters zeroed by hipMemsetAsync each launch.
__device__ __forceinline__ void grid_barrier(unsigned* cnt) {
    __syncthreads();
    if (threadIdx.x == 0) {
        __threadfence();
        __hip_atomic_fetch_add(cnt, 1u, __ATOMIC_ACQ_REL, __HIP_MEMORY_SCOPE_AGENT);
        while (__hip_atomic_load(cnt, __ATOMIC_ACQUIRE, __HIP_MEMORY_SCOPE_AGENT) < NBLK_P)
            __builtin_amdgcn_s_sleep(8);
        __threadfence();
    }
    __syncthreads();
}

// workspace layout (bytes):
//   P    f32 [5][1024][512]  @ 0          (10 MB)  slices: w1, w2hh, wb, w2hl, w2lh
//   Xh   u16 [1024][512]     @ 10485760   (1 MB)
//   Xl   u16 [1024][512]     @ 11534336   (1 MB)
//   Wh   u16 [3][512][512]   @ 12582912   (1.5 MB)
//   W1l  u16 [512][512]      @ 14155776   (0.5 MB)
//   cnt  u32 [2]             @ 16777216   (zeroed per launch)

#define LSTR 72

// ---------------------------------------------------------------------------
// Persistent fused kernel: convert -> gridbar -> 5-slice GEMM -> gridbar ->
// epilogue.  GEMM (r7-proven): 64x64 tile, BK=64, dbuf LDS, 4 waves (2x2),
// wave tile 32x32. Slices: z0 Xh*W0h->P0(w1), z1 Xh*W1h->P1, z2 Xh*W2h->P2(wb),
// z3 Xh*W1l->P3, z4 Xl*W1h->P4;  w2 = P1+P3+P4 (split precision kills the
// w2~0 rsqrt(eps) cliff). C-write self-calibrates via two probe MFMAs.
// ---------------------------------------------------------------------------
__global__ __launch_bounds__(256) void fused_kernel(
    const float* __restrict__ X,
    const float* __restrict__ W0,
    const float* __restrict__ W1,
    const float* __restrict__ W2,
    float* __restrict__ Y,
    float* __restrict__ P,
    unsigned short* __restrict__ Xh,
    unsigned short* __restrict__ Xl,
    unsigned short* __restrict__ Wh,
    unsigned short* __restrict__ W1l,
    unsigned* __restrict__ cnt)
{
    __shared__ __align__(16) unsigned short SA[2][64 * LSTR];
    __shared__ __align__(16) unsigned short SB[2][64 * LSTR];
    __shared__ float red[6][4];

    const int tid = threadIdx.x;
    const int bid = blockIdx.x;

    // ============================ Phase A: convert =========================
    {
        constexpr int NX4  = T_TOK * D / 4;          // 131072
        constexpr int NW4  = D * D / 4;              // 65536
        constexpr int NTOT = NX4 + 3 * NW4;          // 327680
        #pragma unroll
        for (int rep = 0; rep < 3; ++rep) {
            const int i = bid * 256 + tid + rep * (NBLK_P * 256);
            if (i >= NTOT) break;
            if (i < NX4) {
                float4 v = reinterpret_cast<const float4*>(X)[i];
                unsigned short h0 = f2bf(v.x), h1 = f2bf(v.y),
                               h2 = f2bf(v.z), h3 = f2bf(v.w);
                ushort4 h = {h0, h1, h2, h3};
                ushort4 l = {f2bf(v.x - bf2f(h0)), f2bf(v.y - bf2f(h1)),
                             f2bf(v.z - bf2f(h2)), f2bf(v.w - bf2f(h3))};
                reinterpret_cast<ushort4*>(Xh)[i] = h;
                reinterpret_cast<ushort4*>(Xl)[i] = l;
            } else {
                int w = i - NX4;
                int z = w / NW4;
                int j = w - z * NW4;
                const float* Wsrc = (z == 0) ? W0 : (z == 1) ? W1 : W2;
                float4 v = reinterpret_cast<const float4*>(Wsrc)[j];
                unsigned short h0 = f2bf(v.x), h1 = f2bf(v.y),
                               h2 = f2bf(v.z), h3 = f2bf(v.w);
                ushort4 h = {h0, h1, h2, h3};
                reinterpret_cast<ushort4*>(Wh)[w] = h;
                if (z == 1) {
                    ushort4 l = {f2bf(v.x - bf2f(h0)), f2bf(v.y - bf2f(h1)),
                                 f2bf(v.z - bf2f(h2)), f2bf(v.w - bf2f(h3))};
                    reinterpret_cast<ushort4*>(W1l)[j] = l;
                }
            }
        }
    }
    grid_barrier(cnt);

    // ============================ Phase B: GEMM ============================
    {
        const int lane = tid & 63;
        const int wid  = tid >> 6;
        const int wr   = wid >> 1;
        const int wc   = wid & 1;
        const int l15  = lane & 15;
        const int l4   = lane >> 4;

        // layout probes (job-independent): D1[m][n]=m, D2[m][n]=n
        bf16x8 aP1 = {}, bP1 = {}, aP2 = {}, bP2 = {};
        if (l4 == 0) {
            aP1[0] = (short)f2bf((float)l15);
            bP1[0] = (short)f2bf(1.0f);
            aP2[0] = (short)f2bf(1.0f);
            bP2[0] = (short)f2bf((float)l15);
        }
        f32x4 zero = {};
        f32x4 D1 = __builtin_amdgcn_mfma_f32_16x16x32_bf16(aP1, bP1, zero, 0, 0, 0);
        f32x4 D2 = __builtin_amdgcn_mfma_f32_16x16x32_bf16(aP2, bP2, zero, 0, 0, 0);
        int mi[4], ni[4];
        #pragma unroll
        for (int r = 0; r < 4; ++r) { mi[r] = (int)D1[r]; ni[r] = (int)D2[r]; }

        const int srow = tid >> 3;
        const int scol = (tid & 7) * 8;

        for (int job = bid; job < 640; job += NBLK_P) {
            const int z   = job >> 7;          // 0..4
            const int rem = job & 127;
            const int bm  = (rem & 15) * 64;
            const int bn  = (rem >> 4) * 64;

            const unsigned short* __restrict__ A = (z == 4) ? Xl : Xh;
            const unsigned short* __restrict__ B =
                (z == 3) ? W1l : Wh + (size_t)(z == 4 ? 1 : z) * D * D;

            const size_t ga0 = (size_t)(bm + srow) * D + scol;
            const size_t ga1 = (size_t)(bm + srow + 32) * D + scol;
            const size_t gb0 = (size_t)(bn + srow) * D + scol;
            const size_t gb1 = (size_t)(bn + srow + 32) * D + scol;

            f32x4 acc[2][2] = {};
            bf16x8 va0, va1, vb0, vb1;

            va0 = *reinterpret_cast<const bf16x8*>(A + ga0);
            va1 = *reinterpret_cast<const bf16x8*>(A + ga1);
            vb0 = *reinterpret_cast<const bf16x8*>(B + gb0);
            vb1 = *reinterpret_cast<const bf16x8*>(B + gb1);
            *reinterpret_cast<bf16x8*>(&SA[0][srow * LSTR + scol])        = va0;
            *reinterpret_cast<bf16x8*>(&SA[0][(srow + 32) * LSTR + scol]) = va1;
            *reinterpret_cast<bf16x8*>(&SB[0][srow * LSTR + scol])        = vb0;
            *reinterpret_cast<bf16x8*>(&SB[0][(srow + 32) * LSTR + scol]) = vb1;
            __syncthreads();

            int cur = 0;
            #pragma unroll
            for (int t = 0; t < 8; ++t) {
                if (t < 7) {
                    const int k0 = (t + 1) * 64;
                    va0 = *reinterpret_cast<const bf16x8*>(A + ga0 + k0);
                    va1 = *reinterpret_cast<const bf16x8*>(A + ga1 + k0);
                    vb0 = *reinterpret_cast<const bf16x8*>(B + gb0 + k0);
                    vb1 = *reinterpret_cast<const bf16x8*>(B + gb1 + k0);
                }

                #pragma unroll
                for (int kc = 0; kc < 2; ++kc) {
                    const int ko = kc * 32 + l4 * 8;
                    bf16x8 a0 = *reinterpret_cast<const bf16x8*>(
                        &SA[cur][(wr * 32 + l15) * LSTR + ko]);
                    bf16x8 a1 = *reinterpret_cast<const bf16x8*>(
                        &SA[cur][(wr * 32 + 16 + l15) * LSTR + ko]);
                    bf16x8 b0 = *reinterpret_cast<const bf16x8*>(
                        &SB[cur][(wc * 32 + l15) * LSTR + ko]);
                    bf16x8 b1 = *reinterpret_cast<const bf16x8*>(
                        &SB[cur][(wc * 32 + 16 + l15) * LSTR + ko]);
                    acc[0][0] = __builtin_amdgcn_mfma_f32_16x16x32_bf16(a0, b0, acc[0][0], 0, 0, 0);
                    acc[0][1] = __builtin_amdgcn_mfma_f32_16x16x32_bf16(a0, b1, acc[0][1], 0, 0, 0);
                    acc[1][0] = __builtin_amdgcn_mfma_f32_16x16x32_bf16(a1, b0, acc[1][0], 0, 0, 0);
                    acc[1][1] = __builtin_amdgcn_mfma_f32_16x16x32_bf16(a1, b1, acc[1][1], 0, 0, 0);
                }

                if (t < 7) {
                    const int nxt = cur ^ 1;
                    *reinterpret_cast<bf16x8*>(&SA[nxt][srow * LSTR + scol])        = va0;
                    *reinterpret_cast<bf16x8*>(&SA[nxt][(srow + 32) * LSTR + scol]) = va1;
                    *reinterpret_cast<bf16x8*>(&SB[nxt][srow * LSTR + scol])        = vb0;
                    *reinterpret_cast<bf16x8*>(&SB[nxt][(srow + 32) * LSTR + scol]) = vb1;
                    __syncthreads();
                    cur = nxt;
                }
            }

            float* __restrict__ Pz = P + (size_t)z * T_TOK * D;
            #pragma unroll
            for (int fm = 0; fm < 2; ++fm)
                #pragma unroll
                for (int fn = 0; fn < 2; ++fn)
                    #pragma unroll
                    for (int r = 0; r < 4; ++r) {
                        int row = bm + wr * 32 + fm * 16 + mi[r];
                        int col = bn + wc * 32 + fn * 16 + ni[r];
                        Pz[(size_t)row * D + col] = acc[fm][fn][r];
                    }
        }
    }
    grid_barrier(cnt + 64);

    // ============================ Phase C: epilogue ========================
    constexpr size_t SL = (size_t)T_TOK * D;
    for (int t = bid; t < T_TOK; t += NBLK_P) {
        const float2* __restrict__ w1 = (const float2*)(P          + (size_t)t * D);
        const float2* __restrict__ p1 = (const float2*)(P + SL     + (size_t)t * D);
        const float2* __restrict__ wb = (const float2*)(P + SL * 2 + (size_t)t * D);
        const float2* __restrict__ p3 = (const float2*)(P + SL * 3 + (size_t)t * D);
        const float2* __restrict__ p4 = (const float2*)(P + SL * 4 + (size_t)t * D);
        const float2* __restrict__ x  = (const float2*)(X          + (size_t)t * D);

        float2 xv  = x[tid];
        float2 w1v = w1[tid];
        float2 wbv = wb[tid];

        float sx  = xv.x + xv.y;
        float s1  = w1v.x + w1v.y;
        float q1  = w1v.x * w1v.x + w1v.y * w1v.y;
        float d1x = w1v.x * xv.x + w1v.y * xv.y;
        float sb  = wbv.x + wbv.y;
        float qb  = wbv.x * wbv.x + wbv.y * wbv.y;

        #pragma unroll
        for (int off = 32; off > 0; off >>= 1) {
            sx  += __shfl_down(sx,  off);
            s1  += __shfl_down(s1,  off);
            q1  += __shfl_down(q1,  off);
            d1x += __shfl_down(d1x, off);
            sb  += __shfl_down(sb,  off);
            qb  += __shfl_down(qb,  off);
        }

        const int wave = tid >> 6;
        if ((tid & 63) == 0) {
            red[0][wave] = sx;  red[1][wave] = s1;  red[2][wave] = q1;
            red[3][wave] = d1x; red[4][wave] = sb;  red[5][wave] = qb;
        }
        __syncthreads();
        sx  = red[0][0] + red[0][1] + red[0][2] + red[0][3];
        s1  = red[1][0] + red[1][1] + red[1][2] + red[1][3];
        q1  = red[2][0] + red[2][1] + red[2][2] + red[2][3];
        d1x = red[3][0] + red[3][1] + red[3][2] + red[3][3];
        sb  = red[4][0] + red[4][1] + red[4][2] + red[4][3];
        qb  = red[5][0] + red[5][1] + red[5][2] + red[5][3];
        __syncthreads();   // protect red[] before next loop iteration

        const float inv_d = 1.f / (float)D;
        const float mu1   = s1 * inv_d;
        const float var1  = q1 * inv_d - mu1 * mu1;
        const float Sv    = d1x - mu1 * sx;
        const float mub   = sb * inv_d;
        const float varb  = qb * inv_d - mub * mub;
        const float rb    = rsqrtf(varb + EPS);

        float2 a = p1[tid], b = p3[tid], c = p4[tid];
        float2 w2v = {a.x + b.x + c.x, a.y + b.y + c.y};
        float2 y;
        y.x = w2v.x * Sv * rsqrtf(w2v.x * w2v.x * var1 + EPS) + (wbv.x - mub) * rb;
        y.y = w2v.y * Sv * rsqrtf(w2v.y * w2v.y * var1 + EPS) + (wbv.y - mub) * rb;
        reinterpret_cast<float2*>(Y + (size_t)t * D)[tid] = y;
    }
}

extern "C" void kernel_launch(void* const* d_in, const int* in_sizes, int n_in,
                              void* d_out, int out_size, void* d_ws, size_t ws_size,
                              hipStream_t stream) {
    const float* x     = (const float*)d_in[0];
    const float* W_in  = (const float*)d_in[1];
    const float* W_out = (const float*)d_in[2];
    const float* W_b   = (const float*)d_in[3];
    float* Y = (float*)d_out;

    char* ws = (char*)d_ws;
    float*          P   = (float*)(ws);                        // 10 MB
    unsigned short* Xh  = (unsigned short*)(ws + 10485760);    // 1 MB
    unsigned short* Xl  = (unsigned short*)(ws + 11534336);    // 1 MB
    unsigned short* Wh  = (unsigned short*)(ws + 12582912);    // 1.5 MB
    unsigned short* W1l = (unsigned short*)(ws + 14155776);    // 0.5 MB
    unsigned*       cnt = (unsigned*)(ws + 16777216);          // 2 counters (256B apart)

    // zero barrier counters (graph-capturable, deterministic per replay)
    hipMemsetAsync(cnt, 0, 512, stream);

    fused_kernel<<<dim3(NBLK_P), 256, 0, stream>>>(
        x, W_in, W_out, W_b, Y, P, Xh, Xl, Wh, W1l, cnt);
}

// Round 11
// 23.417 us; speedup vs baseline: 7.3781x; 7.3781x over previous
//
#include <hip/hip_runtime.h>
#include <math.h>

#define T_TOK 1024   // B*S
#define D 512        // D_IN = D_OUT
#define EPS 1e-5f
#define LSTR 72      // bf16 elems per LDS row (64 + 8 pad)

typedef short bf16x8 __attribute__((ext_vector_type(8)));
typedef float f32x4  __attribute__((ext_vector_type(4)));

__device__ __forceinline__ unsigned short f2bf(float f) {
    unsigned int u = __builtin_bit_cast(unsigned int, f);
    u += 0x7FFFu + ((u >> 16) & 1u);   // RNE
    return (unsigned short)(u >> 16);
}
__device__ __forceinline__ float bf2f(unsigned short h) {
    return __builtin_bit_cast(float, (unsigned int)h << 16);
}

// pack 8 fp32 -> 8 bf16; lo=true packs the exact residual (v - bf16(v))
__device__ __forceinline__ bf16x8 pack8(float4 u0, float4 u1, bool lo) {
    float v[8] = {u0.x, u0.y, u0.z, u0.w, u1.x, u1.y, u1.z, u1.w};
    bf16x8 r;
    #pragma unroll
    for (int j = 0; j < 8; ++j) {
        unsigned short h = f2bf(v[j]);
        r[j] = (short)(lo ? f2bf(v[j] - bf2f(h)) : h);
    }
    return r;
}

// workspace layout: P f32 [5][1024][512] @ 0 (10 MB)
//   slices: z0 Xh*W0h (w1) | z1 Xh*W1h | z2 Xh*W2h (wb) | z3 Xh*W1l | z4 Xl*W1h
//   epilogue: w2 = P1 + P3 + P4  (split precision kills the w2~0 rsqrt(eps)
//   cliff: step width sqrt(eps/var1)~0.0055 < plain-bf16 GEMM abs error)

// ---------------------------------------------------------------------------
// Kernel 1: 5-slice bf16 MFMA GEMM staging DIRECTLY from fp32 sources
// (fp32->bf16 conversion fused into the LDS write phase; each block's
// conversion mode is uniform). r7 geometry: 64x64 tile, BK=64, dbuf LDS,
// 4 waves (2x2), wave tile 32x32 (2x2 fragments), 1 barrier per k-step.
// C-write self-calibrates via two probe MFMAs (correct under any
// self-consistent HW fragment layout).
// ---------------------------------------------------------------------------
__global__ __launch_bounds__(256) void gemm_direct(
    const float* __restrict__ X,
    const float* __restrict__ W0,
    const float* __restrict__ W1,
    const float* __restrict__ W2,
    float* __restrict__ P)
{
    __shared__ __align__(16) unsigned short SA[2][64 * LSTR];
    __shared__ __align__(16) unsigned short SB[2][64 * LSTR];

    const int tid  = threadIdx.x;
    const int lane = tid & 63;
    const int wid  = tid >> 6;
    const int wr   = wid >> 1;
    const int wc   = wid & 1;
    const int bm   = blockIdx.x * 64;
    const int bn   = blockIdx.y * 64;
    const int z    = blockIdx.z;
    const int l15  = lane & 15;
    const int l4   = lane >> 4;

    const float* __restrict__ B = (z == 0) ? W0 : (z == 2) ? W2 : W1;
    const bool alo = (z == 4);
    const bool blo = (z == 3);

    // --- layout probes: D1[m][n]=m, D2[m][n]=n under the load convention ---
    bf16x8 aP1 = {}, bP1 = {}, aP2 = {}, bP2 = {};
    if (l4 == 0) {
        aP1[0] = (short)f2bf((float)l15);
        bP1[0] = (short)f2bf(1.0f);
        aP2[0] = (short)f2bf(1.0f);
        bP2[0] = (short)f2bf((float)l15);
    }
    f32x4 zero = {};
    f32x4 D1 = __builtin_amdgcn_mfma_f32_16x16x32_bf16(aP1, bP1, zero, 0, 0, 0);
    f32x4 D2 = __builtin_amdgcn_mfma_f32_16x16x32_bf16(aP2, bP2, zero, 0, 0, 0);
    int mi[4], ni[4];
    #pragma unroll
    for (int r = 0; r < 4; ++r) { mi[r] = (int)D1[r]; ni[r] = (int)D2[r]; }

    // staging coords: thread covers rows {srow, srow+32} of A and B,
    // 8 floats at col scol each
    const int srow = tid >> 3;          // 0..31
    const int scol = (tid & 7) * 8;     // 0..56
    const size_t ga0 = (size_t)(bm + srow) * D + scol;
    const size_t ga1 = ga0 + (size_t)32 * D;
    const size_t gb0 = (size_t)(bn + srow) * D + scol;
    const size_t gb1 = gb0 + (size_t)32 * D;

    f32x4 acc[2][2] = {};
    float4 a00, a01, a10, a11, b00, b01, b10, b11;

    // prologue: tile 0 -> regs -> convert -> LDS[0]
    a00 = *reinterpret_cast<const float4*>(X + ga0);
    a01 = *reinterpret_cast<const float4*>(X + ga0 + 4);
    a10 = *reinterpret_cast<const float4*>(X + ga1);
    a11 = *reinterpret_cast<const float4*>(X + ga1 + 4);
    b00 = *reinterpret_cast<const float4*>(B + gb0);
    b01 = *reinterpret_cast<const float4*>(B + gb0 + 4);
    b10 = *reinterpret_cast<const float4*>(B + gb1);
    b11 = *reinterpret_cast<const float4*>(B + gb1 + 4);
    *reinterpret_cast<bf16x8*>(&SA[0][srow * LSTR + scol])        = pack8(a00, a01, alo);
    *reinterpret_cast<bf16x8*>(&SA[0][(srow + 32) * LSTR + scol]) = pack8(a10, a11, alo);
    *reinterpret_cast<bf16x8*>(&SB[0][srow * LSTR + scol])        = pack8(b00, b01, blo);
    *reinterpret_cast<bf16x8*>(&SB[0][(srow + 32) * LSTR + scol]) = pack8(b10, b11, blo);
    __syncthreads();

    int cur = 0;
    #pragma unroll
    for (int t = 0; t < 8; ++t) {
        if (t < 7) {
            const int k0 = (t + 1) * 64;
            a00 = *reinterpret_cast<const float4*>(X + ga0 + k0);
            a01 = *reinterpret_cast<const float4*>(X + ga0 + k0 + 4);
            a10 = *reinterpret_cast<const float4*>(X + ga1 + k0);
            a11 = *reinterpret_cast<const float4*>(X + ga1 + k0 + 4);
            b00 = *reinterpret_cast<const float4*>(B + gb0 + k0);
            b01 = *reinterpret_cast<const float4*>(B + gb0 + k0 + 4);
            b10 = *reinterpret_cast<const float4*>(B + gb1 + k0);
            b11 = *reinterpret_cast<const float4*>(B + gb1 + k0 + 4);
        }

        #pragma unroll
        for (int kc = 0; kc < 2; ++kc) {
            const int ko = kc * 32 + l4 * 8;
            bf16x8 fa0 = *reinterpret_cast<const bf16x8*>(
                &SA[cur][(wr * 32 + l15) * LSTR + ko]);
            bf16x8 fa1 = *reinterpret_cast<const bf16x8*>(
                &SA[cur][(wr * 32 + 16 + l15) * LSTR + ko]);
            bf16x8 fb0 = *reinterpret_cast<const bf16x8*>(
                &SB[cur][(wc * 32 + l15) * LSTR + ko]);
            bf16x8 fb1 = *reinterpret_cast<const bf16x8*>(
                &SB[cur][(wc * 32 + 16 + l15) * LSTR + ko]);
            acc[0][0] = __builtin_amdgcn_mfma_f32_16x16x32_bf16(fa0, fb0, acc[0][0], 0, 0, 0);
            acc[0][1] = __builtin_amdgcn_mfma_f32_16x16x32_bf16(fa0, fb1, acc[0][1], 0, 0, 0);
            acc[1][0] = __builtin_amdgcn_mfma_f32_16x16x32_bf16(fa1, fb0, acc[1][0], 0, 0, 0);
            acc[1][1] = __builtin_amdgcn_mfma_f32_16x16x32_bf16(fa1, fb1, acc[1][1], 0, 0, 0);
        }

        if (t < 7) {
            const int nxt = cur ^ 1;
            *reinterpret_cast<bf16x8*>(&SA[nxt][srow * LSTR + scol])        = pack8(a00, a01, alo);
            *reinterpret_cast<bf16x8*>(&SA[nxt][(srow + 32) * LSTR + scol]) = pack8(a10, a11, alo);
            *reinterpret_cast<bf16x8*>(&SB[nxt][srow * LSTR + scol])        = pack8(b00, b01, blo);
            *reinterpret_cast<bf16x8*>(&SB[nxt][(srow + 32) * LSTR + scol]) = pack8(b10, b11, blo);
            __syncthreads();
            cur = nxt;
        }
    }

    float* __restrict__ Pz = P + (size_t)z * T_TOK * D;
    #pragma unroll
    for (int fm = 0; fm < 2; ++fm)
        #pragma unroll
        for (int fn = 0; fn < 2; ++fn)
            #pragma unroll
            for (int r = 0; r < 4; ++r) {
                int row = bm + wr * 32 + fm * 16 + mi[r];
                int col = bn + wc * 32 + fn * 16 + ni[r];
                Pz[(size_t)row * D + col] = acc[fm][fn][r];
            }
}

// ---------------------------------------------------------------------------
// Kernel 2: per-token epilogue via rank-1 layernorm collapse.
//   w1 = P0, wb = P2, w2 = P1 + P3 + P4
//   y[i] = w2[i]*S*rsqrt(w2[i]^2*var1+eps) + (wb[i]-mu_b)*rsqrt(var_b+eps)
//   S = <w1,x> - mean(w1)*sum(x)
// ---------------------------------------------------------------------------
__global__ __launch_bounds__(256) void epilogue_kernel(
    const float* __restrict__ X,
    const float* __restrict__ P,    // [5][T_TOK][D]
    float* __restrict__ Y)
{
    const int t   = blockIdx.x;
    const int tid = threadIdx.x;
    constexpr size_t SL = (size_t)T_TOK * D;

    const float2* __restrict__ w1 = (const float2*)(P          + (size_t)t * D);
    const float2* __restrict__ p1 = (const float2*)(P + SL     + (size_t)t * D);
    const float2* __restrict__ wb = (const float2*)(P + SL * 2 + (size_t)t * D);
    const float2* __restrict__ p3 = (const float2*)(P + SL * 3 + (size_t)t * D);
    const float2* __restrict__ p4 = (const float2*)(P + SL * 4 + (size_t)t * D);
    const float2* __restrict__ x  = (const float2*)(X          + (size_t)t * D);

    float2 xv  = x[tid];
    float2 w1v = w1[tid];
    float2 wbv = wb[tid];

    float sx  = xv.x + xv.y;
    float s1  = w1v.x + w1v.y;
    float q1  = w1v.x * w1v.x + w1v.y * w1v.y;
    float d1x = w1v.x * xv.x + w1v.y * xv.y;
    float sb  = wbv.x + wbv.y;
    float qb  = wbv.x * wbv.x + wbv.y * wbv.y;

    #pragma unroll
    for (int off = 32; off > 0; off >>= 1) {
        sx  += __shfl_down(sx,  off);
        s1  += __shfl_down(s1,  off);
        q1  += __shfl_down(q1,  off);
        d1x += __shfl_down(d1x, off);
        sb  += __shfl_down(sb,  off);
        qb  += __shfl_down(qb,  off);
    }

    __shared__ float red[6][4];
    const int wave = tid >> 6;
    if ((tid & 63) == 0) {
        red[0][wave] = sx;  red[1][wave] = s1;  red[2][wave] = q1;
        red[3][wave] = d1x; red[4][wave] = sb;  red[5][wave] = qb;
    }
    __syncthreads();
    sx  = red[0][0] + red[0][1] + red[0][2] + red[0][3];
    s1  = red[1][0] + red[1][1] + red[1][2] + red[1][3];
    q1  = red[2][0] + red[2][1] + red[2][2] + red[2][3];
    d1x = red[3][0] + red[3][1] + red[3][2] + red[3][3];
    sb  = red[4][0] + red[4][1] + red[4][2] + red[4][3];
    qb  = red[5][0] + red[5][1] + red[5][2] + red[5][3];

    const float inv_d = 1.f / (float)D;
    const float mu1   = s1 * inv_d;
    const float var1  = q1 * inv_d - mu1 * mu1;
    const float Sv    = d1x - mu1 * sx;
    const float mub   = sb * inv_d;
    const float varb  = qb * inv_d - mub * mub;
    const float rb    = rsqrtf(varb + EPS);

    float2 a = p1[tid], b = p3[tid], c = p4[tid];
    float2 w2v = {a.x + b.x + c.x, a.y + b.y + c.y};
    float2 y;
    y.x = w2v.x * Sv * rsqrtf(w2v.x * w2v.x * var1 + EPS) + (wbv.x - mub) * rb;
    y.y = w2v.y * Sv * rsqrtf(w2v.y * w2v.y * var1 + EPS) + (wbv.y - mub) * rb;
    reinterpret_cast<float2*>(Y + (size_t)t * D)[tid] = y;
}

extern "C" void kernel_launch(void* const* d_in, const int* in_sizes, int n_in,
                              void* d_out, int out_size, void* d_ws, size_t ws_size,
                              hipStream_t stream) {
    const float* x     = (const float*)d_in[0];
    const float* W_in  = (const float*)d_in[1];
    const float* W_out = (const float*)d_in[2];
    const float* W_b   = (const float*)d_in[3];
    float* Y = (float*)d_out;
    float* P = (float*)d_ws;   // 5*1024*512*4 = 10 MB

    gemm_direct<<<dim3(T_TOK / 64, D / 64, 5), 256, 0, stream>>>(
        x, W_in, W_out, W_b, P);

    epilogue_kernel<<<dim3(T_TOK), 256, 0, stream>>>(x, P, Y);
}

// Round 12
// 20.968 us; speedup vs baseline: 8.2399x; 1.1168x over previous
//
#include <hip/hip_runtime.h>
#include <math.h>

#define T_TOK 1024   // B*S
#define D 512        // D_IN = D_OUT
#define EPS 1e-5f
#define LSTR 72      // bf16 elems per LDS row (64 + 8 pad)

typedef short bf16x8 __attribute__((ext_vector_type(8)));
typedef __bf16 bf8v  __attribute__((ext_vector_type(8)));
typedef float f32x4  __attribute__((ext_vector_type(4)));

__device__ __forceinline__ unsigned short f2bf(float f) {   // probes only
    unsigned int u = __builtin_bit_cast(unsigned int, f);
    u += 0x7FFFu + ((u >> 16) & 1u);   // RNE
    return (unsigned short)(u >> 16);
}

// pack 8 fp32 -> 8 bf16 via native __bf16 casts (compiler emits HW
// v_cvt_pk_bf16_f32, RNE). lo=true packs the exact fp32 residual.
__device__ __forceinline__ bf16x8 pack8(float4 u0, float4 u1, bool lo) {
    float v[8] = {u0.x, u0.y, u0.z, u0.w, u1.x, u1.y, u1.z, u1.w};
    bf8v r;
    if (!lo) {
        #pragma unroll
        for (int j = 0; j < 8; ++j) r[j] = (__bf16)v[j];
    } else {
        #pragma unroll
        for (int j = 0; j < 8; ++j) {
            __bf16 h = (__bf16)v[j];
            r[j] = (__bf16)(v[j] - (float)h);
        }
    }
    return __builtin_bit_cast(bf16x8, r);
}

// workspace layout: P f32 [5][1024][512] @ 0 (10 MB)
//   slices: z0 Xh*W0h (w1) | z1 Xh*W1h | z2 Xh*W2h (wb) | z3 Xh*W1l | z4 Xl*W1h
//   epilogue: w2 = P1 + P3 + P4  (split precision kills the w2~0 rsqrt(eps)
//   cliff: step width sqrt(eps/var1)~0.0055 < plain-bf16 GEMM abs error)

// ---------------------------------------------------------------------------
// Kernel 1: 5-slice bf16 MFMA GEMM staging DIRECTLY from fp32 sources
// (fp32->bf16 conversion fused into the LDS write phase via HW cvt).
// r7 geometry: 64x64 tile, BK=64, dbuf LDS, 4 waves (2x2), wave tile 32x32
// (2x2 fragments), 1 barrier per k-step, reg prefetch of tile t+1.
// C-write self-calibrates via two probe MFMAs (correct under any
// self-consistent HW fragment layout).
// ---------------------------------------------------------------------------
__global__ __launch_bounds__(256) void gemm_direct(
    const float* __restrict__ X,
    const float* __restrict__ W0,
    const float* __restrict__ W1,
    const float* __restrict__ W2,
    float* __restrict__ P)
{
    __shared__ __align__(16) unsigned short SA[2][64 * LSTR];
    __shared__ __align__(16) unsigned short SB[2][64 * LSTR];

    const int tid  = threadIdx.x;
    const int lane = tid & 63;
    const int wid  = tid >> 6;
    const int wr   = wid >> 1;
    const int wc   = wid & 1;
    const int bm   = blockIdx.x * 64;
    const int bn   = blockIdx.y * 64;
    const int z    = blockIdx.z;
    const int l15  = lane & 15;
    const int l4   = lane >> 4;

    const float* __restrict__ B = (z == 0) ? W0 : (z == 2) ? W2 : W1;
    const bool alo = (z == 4);
    const bool blo = (z == 3);

    // --- layout probes: D1[m][n]=m, D2[m][n]=n under the load convention ---
    bf16x8 aP1 = {}, bP1 = {}, aP2 = {}, bP2 = {};
    if (l4 == 0) {
        aP1[0] = (short)f2bf((float)l15);
        bP1[0] = (short)f2bf(1.0f);
        aP2[0] = (short)f2bf(1.0f);
        bP2[0] = (short)f2bf((float)l15);
    }
    f32x4 zero = {};
    f32x4 D1 = __builtin_amdgcn_mfma_f32_16x16x32_bf16(aP1, bP1, zero, 0, 0, 0);
    f32x4 D2 = __builtin_amdgcn_mfma_f32_16x16x32_bf16(aP2, bP2, zero, 0, 0, 0);
    int mi[4], ni[4];
    #pragma unroll
    for (int r = 0; r < 4; ++r) { mi[r] = (int)D1[r]; ni[r] = (int)D2[r]; }

    // staging coords: thread covers rows {srow, srow+32} of A and B,
    // 8 floats at col scol each
    const int srow = tid >> 3;          // 0..31
    const int scol = (tid & 7) * 8;     // 0..56
    const size_t ga0 = (size_t)(bm + srow) * D + scol;
    const size_t ga1 = ga0 + (size_t)32 * D;
    const size_t gb0 = (size_t)(bn + srow) * D + scol;
    const size_t gb1 = gb0 + (size_t)32 * D;

    f32x4 acc[2][2] = {};
    float4 a00, a01, a10, a11, b00, b01, b10, b11;

    // prologue: tile 0 -> regs -> convert -> LDS[0]
    a00 = *reinterpret_cast<const float4*>(X + ga0);
    a01 = *reinterpret_cast<const float4*>(X + ga0 + 4);
    a10 = *reinterpret_cast<const float4*>(X + ga1);
    a11 = *reinterpret_cast<const float4*>(X + ga1 + 4);
    b00 = *reinterpret_cast<const float4*>(B + gb0);
    b01 = *reinterpret_cast<const float4*>(B + gb0 + 4);
    b10 = *reinterpret_cast<const float4*>(B + gb1);
    b11 = *reinterpret_cast<const float4*>(B + gb1 + 4);
    *reinterpret_cast<bf16x8*>(&SA[0][srow * LSTR + scol])        = pack8(a00, a01, alo);
    *reinterpret_cast<bf16x8*>(&SA[0][(srow + 32) * LSTR + scol]) = pack8(a10, a11, alo);
    *reinterpret_cast<bf16x8*>(&SB[0][srow * LSTR + scol])        = pack8(b00, b01, blo);
    *reinterpret_cast<bf16x8*>(&SB[0][(srow + 32) * LSTR + scol]) = pack8(b10, b11, blo);
    __syncthreads();

    int cur = 0;
    #pragma unroll
    for (int t = 0; t < 8; ++t) {
        if (t < 7) {
            const int k0 = (t + 1) * 64;
            a00 = *reinterpret_cast<const float4*>(X + ga0 + k0);
            a01 = *reinterpret_cast<const float4*>(X + ga0 + k0 + 4);
            a10 = *reinterpret_cast<const float4*>(X + ga1 + k0);
            a11 = *reinterpret_cast<const float4*>(X + ga1 + k0 + 4);
            b00 = *reinterpret_cast<const float4*>(B + gb0 + k0);
            b01 = *reinterpret_cast<const float4*>(B + gb0 + k0 + 4);
            b10 = *reinterpret_cast<const float4*>(B + gb1 + k0);
            b11 = *reinterpret_cast<const float4*>(B + gb1 + k0 + 4);
        }

        #pragma unroll
        for (int kc = 0; kc < 2; ++kc) {
            const int ko = kc * 32 + l4 * 8;
            bf16x8 fa0 = *reinterpret_cast<const bf16x8*>(
                &SA[cur][(wr * 32 + l15) * LSTR + ko]);
            bf16x8 fa1 = *reinterpret_cast<const bf16x8*>(
                &SA[cur][(wr * 32 + 16 + l15) * LSTR + ko]);
            bf16x8 fb0 = *reinterpret_cast<const bf16x8*>(
                &SB[cur][(wc * 32 + l15) * LSTR + ko]);
            bf16x8 fb1 = *reinterpret_cast<const bf16x8*>(
                &SB[cur][(wc * 32 + 16 + l15) * LSTR + ko]);
            acc[0][0] = __builtin_amdgcn_mfma_f32_16x16x32_bf16(fa0, fb0, acc[0][0], 0, 0, 0);
            acc[0][1] = __builtin_amdgcn_mfma_f32_16x16x32_bf16(fa0, fb1, acc[0][1], 0, 0, 0);
            acc[1][0] = __builtin_amdgcn_mfma_f32_16x16x32_bf16(fa1, fb0, acc[1][0], 0, 0, 0);
            acc[1][1] = __builtin_amdgcn_mfma_f32_16x16x32_bf16(fa1, fb1, acc[1][1], 0, 0, 0);
        }

        if (t < 7) {
            const int nxt = cur ^ 1;
            *reinterpret_cast<bf16x8*>(&SA[nxt][srow * LSTR + scol])        = pack8(a00, a01, alo);
            *reinterpret_cast<bf16x8*>(&SA[nxt][(srow + 32) * LSTR + scol]) = pack8(a10, a11, alo);
            *reinterpret_cast<bf16x8*>(&SB[nxt][srow * LSTR + scol])        = pack8(b00, b01, blo);
            *reinterpret_cast<bf16x8*>(&SB[nxt][(srow + 32) * LSTR + scol]) = pack8(b10, b11, blo);
            __syncthreads();
            cur = nxt;
        }
    }

    float* __restrict__ Pz = P + (size_t)z * T_TOK * D;
    #pragma unroll
    for (int fm = 0; fm < 2; ++fm)
        #pragma unroll
        for (int fn = 0; fn < 2; ++fn)
            #pragma unroll
            for (int r = 0; r < 4; ++r) {
                int row = bm + wr * 32 + fm * 16 + mi[r];
                int col = bn + wc * 32 + fn * 16 + ni[r];
                Pz[(size_t)row * D + col] = acc[fm][fn][r];
            }
}

// ---------------------------------------------------------------------------
// Kernel 2: per-token epilogue via rank-1 layernorm collapse.
//   w1 = P0, wb = P2, w2 = P1 + P3 + P4
//   y[i] = w2[i]*S*rsqrt(w2[i]^2*var1+eps) + (wb[i]-mu_b)*rsqrt(var_b+eps)
//   S = <w1,x> - mean(w1)*sum(x)
// ---------------------------------------------------------------------------
__global__ __launch_bounds__(256) void epilogue_kernel(
    const float* __restrict__ X,
    const float* __restrict__ P,    // [5][T_TOK][D]
    float* __restrict__ Y)
{
    const int t   = blockIdx.x;
    const int tid = threadIdx.x;
    constexpr size_t SL = (size_t)T_TOK * D;

    const float2* __restrict__ w1 = (const float2*)(P          + (size_t)t * D);
    const float2* __restrict__ p1 = (const float2*)(P + SL     + (size_t)t * D);
    const float2* __restrict__ wb = (const float2*)(P + SL * 2 + (size_t)t * D);
    const float2* __restrict__ p3 = (const float2*)(P + SL * 3 + (size_t)t * D);
    const float2* __restrict__ p4 = (const float2*)(P + SL * 4 + (size_t)t * D);
    const float2* __restrict__ x  = (const float2*)(X          + (size_t)t * D);

    float2 xv  = x[tid];
    float2 w1v = w1[tid];
    float2 wbv = wb[tid];

    float sx  = xv.x + xv.y;
    float s1  = w1v.x + w1v.y;
    float q1  = w1v.x * w1v.x + w1v.y * w1v.y;
    float d1x = w1v.x * xv.x + w1v.y * xv.y;
    float sb  = wbv.x + wbv.y;
    float qb  = wbv.x * wbv.x + wbv.y * wbv.y;

    #pragma unroll
    for (int off = 32; off > 0; off >>= 1) {
        sx  += __shfl_down(sx,  off);
        s1  += __shfl_down(s1,  off);
        q1  += __shfl_down(q1,  off);
        d1x += __shfl_down(d1x, off);
        sb  += __shfl_down(sb,  off);
        qb  += __shfl_down(qb,  off);
    }

    __shared__ float red[6][4];
    const int wave = tid >> 6;
    if ((tid & 63) == 0) {
        red[0][wave] = sx;  red[1][wave] = s1;  red[2][wave] = q1;
        red[3][wave] = d1x; red[4][wave] = sb;  red[5][wave] = qb;
    }
    __syncthreads();
    sx  = red[0][0] + red[0][1] + red[0][2] + red[0][3];
    s1  = red[1][0] + red[1][1] + red[1][2] + red[1][3];
    q1  = red[2][0] + red[2][1] + red[2][2] + red[2][3];
    d1x = red[3][0] + red[3][1] + red[3][2] + red[3][3];
    sb  = red[4][0] + red[4][1] + red[4][2] + red[4][3];
    qb  = red[5][0] + red[5][1] + red[5][2] + red[5][3];

    const float inv_d = 1.f / (float)D;
    const float mu1   = s1 * inv_d;
    const float var1  = q1 * inv_d - mu1 * mu1;
    const float Sv    = d1x - mu1 * sx;
    const float mub   = sb * inv_d;
    const float varb  = qb * inv_d - mub * mub;
    const float rb    = rsqrtf(varb + EPS);

    float2 a = p1[tid], b = p3[tid], c = p4[tid];
    float2 w2v = {a.x + b.x + c.x, a.y + b.y + c.y};
    float2 y;
    y.x = w2v.x * Sv * rsqrtf(w2v.x * w2v.x * var1 + EPS) + (wbv.x - mub) * rb;
    y.y = w2v.y * Sv * rsqrtf(w2v.y * w2v.y * var1 + EPS) + (wbv.y - mub) * rb;
    reinterpret_cast<float2*>(Y + (size_t)t * D)[tid] = y;
}

extern "C" void kernel_launch(void* const* d_in, const int* in_sizes, int n_in,
                              void* d_out, int out_size, void* d_ws, size_t ws_size,
                              hipStream_t stream) {
    const float* x     = (const float*)d_in[0];
    const float* W_in  = (const float*)d_in[1];
    const float* W_out = (const float*)d_in[2];
    const float* W_b   = (const float*)d_in[3];
    float* Y = (float*)d_out;
    float* P = (float*)d_ws;   // 5*1024*512*4 = 10 MB

    gemm_direct<<<dim3(T_TOK / 64, D / 64, 5), 256, 0, stream>>>(
        x, W_in, W_out, W_b, P);

    epilogue_kernel<<<dim3(T_TOK), 256, 0, stream>>>(x, P, Y);
}